// Round 1
// baseline (541.810 us; speedup 1.0000x reference)
//
#include <hip/hip_runtime.h>

#define BATCH  512
#define SEQLEN 256
#define EMB    128
#define HID    128
#define NG     384   // 3*HID

typedef _Float16 f16;
typedef __attribute__((ext_vector_type(8))) _Float16 half8;
typedef __attribute__((ext_vector_type(4))) _Float16 half4f;
typedef __attribute__((ext_vector_type(4))) float    floatx4;

static_assert(sizeof(half8) == 16, "half8 must be 16B");

__device__ __forceinline__ float sigmoidf_(float x) {
    return 1.0f / (1.0f + __expf(-x));
}
__device__ __forceinline__ float tanhf_(float x) {
    return 1.0f - 2.0f / (__expf(2.0f * x) + 1.0f);
}

// ---------------------------------------------------------------------------
// K0: prep — W -> Wt (f16, transposed [j][k]), mask -> maskT [t][b], item gather
// ---------------------------------------------------------------------------
__global__ void prep_kernel(const float* __restrict__ W, const int* __restrict__ mask,
                            const int* __restrict__ mid, const float* __restrict__ emb,
                            f16* __restrict__ Wt, int* __restrict__ maskT,
                            float* __restrict__ item_out) {
    int tid  = blockIdx.x * blockDim.x + threadIdx.x;
    int nthr = gridDim.x * blockDim.x;
    for (int i = tid; i < NG * EMB; i += nthr) {        // Wt[j][k] = W[k][j]
        int j = i >> 7, k = i & 127;
        Wt[i] = (f16)W[k * NG + j];
    }
    for (int i = tid; i < SEQLEN * BATCH; i += nthr) {  // maskT[t][b] = mask[b][t]
        int t = i >> 9, b = i & 511;
        maskT[i] = mask[b * SEQLEN + t];
    }
    for (int i = tid; i < BATCH * EMB; i += nthr) {     // item_emb gather (f32 exact)
        int b = i >> 7, d = i & 127;
        item_out[i] = emb[(size_t)mid[b] * EMB + d];
    }
}

// ---------------------------------------------------------------------------
// K1: x_proj[t][b][j] = emb[mid_hist[b][t]] @ W + b_in   (f16 out, time-major)
// One block per 64-row M-tile (M = B*T = 131072 flat, m = b*256+t).
// 4 waves split N: wave w covers cols w*96..w*96+95. W frags register-resident.
// ---------------------------------------------------------------------------
__global__ __launch_bounds__(256, 2) void xproj_kernel(
        const int* __restrict__ mid_hist, const float* __restrict__ emb,
        const float* __restrict__ bvec, const f16* __restrict__ Wt,
        f16* __restrict__ xws) {
    __shared__ __align__(16) f16 A_lds[64 * 136];   // 64 rows x 128 k, +8 pad
    const int tid   = threadIdx.x;
    const int lane  = tid & 63;
    const int w     = tid >> 6;       // 0..3
    const int l15   = lane & 15;
    const int g4    = lane >> 4;      // 0..3
    const int m0    = blockIdx.x * 64;

    // Stage gathered emb rows as f16 into LDS.
    {
        int r  = tid >> 2;
        int c0 = (tid & 3) * 32;
        int idx = mid_hist[m0 + r];
        const float4* src = (const float4*)(emb + (size_t)idx * EMB + c0);
        #pragma unroll
        for (int i = 0; i < 8; ++i) {
            float4 v = src[i];
            half4f h4 = { (f16)v.x, (f16)v.y, (f16)v.z, (f16)v.w };
            *(half4f*)&A_lds[r * 136 + c0 + i * 4] = h4;
        }
    }

    // B-frags (W) in registers: 6 col-tiles x 4 k-tiles.
    half8 bfr[6][4];
    float bias[6];
    #pragma unroll
    for (int ct = 0; ct < 6; ++ct) {
        int j = w * 96 + ct * 16 + l15;
        bias[ct] = bvec[j];                            // b_in
        #pragma unroll
        for (int kt = 0; kt < 4; ++kt)
            bfr[ct][kt] = *(const half8*)(Wt + j * EMB + kt * 32 + g4 * 8);
    }
    __syncthreads();

    #pragma unroll
    for (int msub = 0; msub < 4; ++msub) {
        half8 afr[4];
        #pragma unroll
        for (int kt = 0; kt < 4; ++kt)
            afr[kt] = *(const half8*)&A_lds[(msub * 16 + l15) * 136 + kt * 32 + g4 * 8];
        #pragma unroll
        for (int ct = 0; ct < 6; ++ct) {
            floatx4 acc = {0.f, 0.f, 0.f, 0.f};
            #pragma unroll
            for (int kt = 0; kt < 4; ++kt)
                acc = __builtin_amdgcn_mfma_f32_16x16x32_f16(afr[kt], bfr[ct][kt], acc, 0, 0, 0);
            int jcol = w * 96 + ct * 16 + l15;
            #pragma unroll
            for (int r = 0; r < 4; ++r) {
                int m = m0 + msub * 16 + g4 * 4 + r;
                int t = m & 255, bq = m >> 8;
                xws[(size_t)(t * BATCH + bq) * NG + jcol] = (f16)(acc[r] + bias[ct]);
            }
        }
    }
}

// ---------------------------------------------------------------------------
// K2: persistent GRU scan. 32 blocks x 512 thr (8 waves). Block owns 16 batch
// rows; wave w owns hidden slice [16w,16w+16). U as register B-frags. h state
// in C-frag-layout registers + f16 LDS copy for A-frags. 2 barriers/step.
// ---------------------------------------------------------------------------
__global__ __launch_bounds__(512, 2) void gru_kernel(
        const float* __restrict__ U, const float* __restrict__ bvec,
        const f16* __restrict__ xws, const int* __restrict__ maskT,
        float* __restrict__ out_user) {
    __shared__ __align__(16) f16 hpk[16 * 136];  // 16 rows x 128 hid, +8 pad
    const int tid   = threadIdx.x;
    const int lane  = tid & 63;
    const int w     = tid >> 6;        // 0..7
    const int l15   = lane & 15;
    const int g4    = lane >> 4;
    const int hid   = w * 16 + l15;    // hidden col 0..127
    const int bbase = blockIdx.x * 16;

    // U frags: 3 gate parts x 4 k-tiles, register resident.
    half8 ufrag[3][4];
    #pragma unroll
    for (int p = 0; p < 3; ++p)
        #pragma unroll
        for (int kt = 0; kt < 4; ++kt) {
            half8 v;
            #pragma unroll
            for (int e = 0; e < 8; ++e) {
                int k = kt * 32 + g4 * 8 + e;
                v[e] = (f16)U[k * NG + p * HID + hid];
            }
            ufrag[p][kt] = v;
        }
    const float bz = bvec[NG + 0 * HID + hid];
    const float br = bvec[NG + 1 * HID + hid];
    const float bh = bvec[NG + 2 * HID + hid];

    for (int i = tid; i < 16 * 136; i += 512) hpk[i] = (f16)0.f;  // h0 = 0

    float hreg[4] = {0.f, 0.f, 0.f, 0.f};
    int aoff[4];
    #pragma unroll
    for (int kt = 0; kt < 4; ++kt) aoff[kt] = l15 * 136 + kt * 32 + g4 * 8;
    int hw_[4], mb[4], xb[12];
    #pragma unroll
    for (int r = 0; r < 4; ++r) {
        int row = g4 * 4 + r;
        hw_[r] = row * 136 + hid;
        mb[r]  = bbase + row;
        #pragma unroll
        for (int p = 0; p < 3; ++p)
            xb[r * 3 + p] = mb[r] * NG + p * HID + hid;
    }

    struct XBuf { f16 x[12]; int m[4]; };
    auto load_x = [&](XBuf& dst, int t) {
        const int tb = t * (BATCH * NG);
        #pragma unroll
        for (int r = 0; r < 4; ++r) {
            #pragma unroll
            for (int p = 0; p < 3; ++p)
                dst.x[r * 3 + p] = xws[tb + xb[r * 3 + p]];
            dst.m[r] = maskT[t * BATCH + mb[r]];
        }
    };

    XBuf xa, xbuf;
    load_x(xa, 0);

    auto step = [&](int t, XBuf& cur, XBuf& nxt) {
        __syncthreads();                               // B1: h_t writes visible
        half8 afr[4];
        #pragma unroll
        for (int kt = 0; kt < 4; ++kt)
            afr[kt] = *(const half8*)&hpk[aoff[kt]];
        int tn = t + 1;
        if (tn < SEQLEN) load_x(nxt, tn);              // prefetch next step
        floatx4 az = {0,0,0,0}, ar = {0,0,0,0}, ah = {0,0,0,0};
        #pragma unroll
        for (int kt = 0; kt < 4; ++kt) {
            az = __builtin_amdgcn_mfma_f32_16x16x32_f16(afr[kt], ufrag[0][kt], az, 0, 0, 0);
            ar = __builtin_amdgcn_mfma_f32_16x16x32_f16(afr[kt], ufrag[1][kt], ar, 0, 0, 0);
            ah = __builtin_amdgcn_mfma_f32_16x16x32_f16(afr[kt], ufrag[2][kt], ah, 0, 0, 0);
        }
        __syncthreads();                               // B2: A-reads done
        #pragma unroll
        for (int r = 0; r < 4; ++r) {
            float z  = sigmoidf_((float)cur.x[r * 3 + 0] + az[r] + bz);
            float rg = sigmoidf_((float)cur.x[r * 3 + 1] + ar[r] + br);
            float hh = tanhf_((float)cur.x[r * 3 + 2] + rg * (ah[r] + bh));
            float hn = z * hreg[r] + (1.f - z) * hh;
            hreg[r]  = cur.m[r] ? hn : hreg[r];
            hpk[hw_[r]] = (f16)hreg[r];                // h_{t+1} (f16 copy)
        }
    };

    for (int t = 0; t < SEQLEN; t += 2) {
        step(t,     xa,   xbuf);
        step(t + 1, xbuf, xa);
    }

    #pragma unroll
    for (int r = 0; r < 4; ++r)
        out_user[(size_t)(bbase + g4 * 4 + r) * HID + hid] = hreg[r];
}

// ---------------------------------------------------------------------------
extern "C" void kernel_launch(void* const* d_in, const int* in_sizes, int n_in,
                              void* d_out, int out_size, void* d_ws, size_t ws_size,
                              hipStream_t stream) {
    const int*   mid      = (const int*)d_in[0];
    const int*   mid_hist = (const int*)d_in[1];
    const int*   mask     = (const int*)d_in[2];
    const float* emb      = (const float*)d_in[3];
    const float* W        = (const float*)d_in[4];
    const float* U        = (const float*)d_in[5];
    const float* bvec     = (const float*)d_in[6];

    float* user_out = (float*)d_out;                   // [512][128]
    float* item_out = (float*)d_out + BATCH * HID;     // [512][128]

    char* ws = (char*)d_ws;
    const size_t XWS_BYTES = (size_t)SEQLEN * BATCH * NG * sizeof(f16);  // 100663296
    f16* xws   = (f16*)ws;
    f16* Wt    = (f16*)(ws + XWS_BYTES);
    int* maskT = (int*)(ws + XWS_BYTES + (size_t)NG * EMB * sizeof(f16));

    prep_kernel <<<256, 256, 0, stream>>>(W, mask, mid, emb, Wt, maskT, item_out);
    xproj_kernel<<<2048, 256, 0, stream>>>(mid_hist, emb, bvec, Wt, xws);
    gru_kernel  <<<32, 512, 0, stream>>>(U, bvec, xws, maskT, user_out);
}

// Round 2
// 398.454 us; speedup vs baseline: 1.3598x; 1.3598x over previous
//
#include <hip/hip_runtime.h>

#define BATCH  512
#define SEQLEN 256
#define EMB    128
#define HID    128
#define LDSROW 136   // padded row stride in f16 elems

typedef _Float16 f16;
typedef __attribute__((ext_vector_type(8))) _Float16 half8;
typedef __attribute__((ext_vector_type(4))) _Float16 half4f;
typedef __attribute__((ext_vector_type(4))) float    floatx4;

__device__ __forceinline__ float fast_sigmoid(float x) {
    return __builtin_amdgcn_rcpf(1.0f + __builtin_amdgcn_exp2f(x * -1.4426950408889634f));
}
__device__ __forceinline__ float fast_tanh(float x) {
    float t = __builtin_amdgcn_exp2f(x * 2.8853900817779268f);
    return 1.0f - 2.0f * __builtin_amdgcn_rcpf(t + 1.0f);
}

// ---------------------------------------------------------------------------
// K0: prep — pack mask bits per (block,t), item_emb gather (f32 exact)
// ---------------------------------------------------------------------------
__global__ void prep_kernel(const int* __restrict__ mask, const int* __restrict__ mid,
                            const float* __restrict__ emb,
                            unsigned* __restrict__ maskP, float* __restrict__ item_out) {
    int tid  = blockIdx.x * blockDim.x + threadIdx.x;
    int nthr = gridDim.x * blockDim.x;
    for (int i = tid; i < 32 * SEQLEN; i += nthr) {      // maskP[blk][t], bit r = row
        int blk = i >> 8, t = i & 255;
        unsigned m = 0;
        #pragma unroll
        for (int r = 0; r < 16; ++r)
            m |= (unsigned)(mask[(blk * 16 + r) * SEQLEN + t] & 1) << r;
        maskP[i] = m;
    }
    for (int i = tid; i < BATCH * EMB; i += nthr) {
        int b = i >> 7, d = i & 127;
        item_out[i] = emb[(size_t)mid[b] * EMB + d];
    }
}

// ---------------------------------------------------------------------------
// K1: fused gather + x-proj + GRU scan. 32 blocks x 512 thr (8 waves).
// Block owns 16 batch rows (b = lane&15 via MFMA B-operand); wave w owns
// hidden cols [16w,16w+16). A-operands (U^T, W^T) register-resident.
// Raw s_barrier + lgkmcnt(0) only — global prefetch stays in flight.
// ---------------------------------------------------------------------------
__global__ __launch_bounds__(512, 1) void gru_fused(
        const int* __restrict__ mid_hist, const float* __restrict__ emb,
        const float* __restrict__ W, const float* __restrict__ U,
        const float* __restrict__ bvec, const unsigned* __restrict__ maskP,
        float* __restrict__ out_user) {
    __shared__ __align__(16) f16 elds[2][16 * LDSROW];  // emb f16, slot = t&1
    __shared__ __align__(16) f16 hpk[16 * LDSROW];      // h state, [b][k]

    const int tid   = threadIdx.x;
    const int lane  = tid & 63;
    const int w     = tid >> 6;        // 0..7
    const int l15   = lane & 15;
    const int g4    = lane >> 4;       // 0..3
    const int blk   = blockIdx.x;
    const int bbase = blk * 16;

    // --- A-frags: rows j = p*128 + w*16 + l15, k = kt*32 + g4*8 + e ---------
    half8 uA[3][4], wA[3][4];
    #pragma unroll
    for (int p = 0; p < 3; ++p)
        #pragma unroll
        for (int kt = 0; kt < 4; ++kt) {
            half8 u, v;
            const int j = p * 128 + w * 16 + l15;
            #pragma unroll
            for (int e = 0; e < 8; ++e) {
                int k = kt * 32 + g4 * 8 + e;
                u[e] = (f16)U[k * 384 + j];
                v[e] = (f16)W[k * 384 + j];
            }
            uA[p][kt] = u; wA[p][kt] = v;
        }

    // --- biases for this thread's 4 j's (jj..jj+3) --------------------------
    const int jj = w * 16 + g4 * 4;
    float bcz[4], bcr[4], bih[4], brh[4];
    {
        float4 a0 = *(const float4*)(bvec + jj);
        float4 a1 = *(const float4*)(bvec + 384 + jj);
        float4 c0 = *(const float4*)(bvec + 128 + jj);
        float4 c1 = *(const float4*)(bvec + 512 + jj);
        float4 d0 = *(const float4*)(bvec + 256 + jj);
        float4 d1 = *(const float4*)(bvec + 640 + jj);
        bcz[0]=a0.x+a1.x; bcz[1]=a0.y+a1.y; bcz[2]=a0.z+a1.z; bcz[3]=a0.w+a1.w;
        bcr[0]=c0.x+c1.x; bcr[1]=c0.y+c1.y; bcr[2]=c0.z+c1.z; bcr[3]=c0.w+c1.w;
        bih[0]=d0.x; bih[1]=d0.y; bih[2]=d0.z; bih[3]=d0.w;
        brh[0]=d1.x; brh[1]=d1.y; brh[2]=d1.z; brh[3]=d1.w;
    }

    // --- staging ids: 32 threads per emb row ---------------------------------
    const int r_e = tid >> 5;          // 0..15 batch row
    const int c_e = (tid & 31) * 4;    // float4 chunk

    for (int i = tid; i < 16 * LDSROW; i += 512) hpk[i] = (f16)0.f;  // h0 = 0

    // prologue: fill slots 0,1 directly
    {
        int i0 = mid_hist[(bbase + r_e) * SEQLEN + 0];
        int i1 = mid_hist[(bbase + r_e) * SEQLEN + 1];
        float4 v0 = *(const float4*)(emb + (size_t)i0 * EMB + c_e);
        float4 v1 = *(const float4*)(emb + (size_t)i1 * EMB + c_e);
        *(half4f*)&elds[0][r_e * LDSROW + c_e] = half4f{(f16)v0.x,(f16)v0.y,(f16)v0.z,(f16)v0.w};
        *(half4f*)&elds[1][r_e * LDSROW + c_e] = half4f{(f16)v1.x,(f16)v1.y,(f16)v1.z,(f16)v1.w};
    }
    __syncthreads();

    // prefetch rings (consumed 2 steps after issue)
    int i2 = mid_hist[(bbase + r_e) * SEQLEN + 2];
    int i3 = mid_hist[(bbase + r_e) * SEQLEN + 3];
    float4   eE   = *(const float4*)(emb + (size_t)i2 * EMB + c_e);  // emb(2)
    float4   eO   = *(const float4*)(emb + (size_t)i3 * EMB + c_e);  // emb(3)
    int      idxE = mid_hist[(bbase + r_e) * SEQLEN + 4];            // idx(4)
    int      idxO = mid_hist[(bbase + r_e) * SEQLEN + 5];            // idx(5)
    unsigned mskE = maskP[blk * SEQLEN + 0];                          // msk(0)
    unsigned mskO = maskP[blk * SEQLEN + 1];                          // msk(1)

    float hreg[4] = {0.f, 0.f, 0.f, 0.f};
    const int aoff  = l15 * LDSROW;            // + kt*32 + g4*8
    const int hwoff = l15 * LDSROW + jj;       // b64 h write

    auto step = [&](int t, int slot, float4& eBuf, int& idxP, unsigned& mskR) {
        // ---- phase 1: frag reads (h_t, emb_t) ----
        half8 ea[4], ha[4];
        const f16* eb = elds[slot];
        #pragma unroll
        for (int kt = 0; kt < 4; ++kt) {
            ea[kt] = *(const half8*)&eb [aoff + kt * 32 + g4 * 8];
            ha[kt] = *(const half8*)&hpk[aoff + kt * 32 + g4 * 8];
        }
        __builtin_amdgcn_sched_barrier(0);
        asm volatile("s_waitcnt lgkmcnt(0)" ::: "memory");   // my reads done
        __builtin_amdgcn_s_barrier();                        // all waves read
        __builtin_amdgcn_sched_barrier(0);

        // ---- phase 2: recycle elds slot with emb(t+2); reissue prefetch ----
        float4 ev = eBuf;                                     // emb(t+2) f32
        *(half4f*)&elds[slot][r_e * LDSROW + c_e] =
            half4f{(f16)ev.x,(f16)ev.y,(f16)ev.z,(f16)ev.w};
        unsigned mval = mskR;                                 // msk(t)
        int ii = idxP;                                        // idx(t+4)
        eBuf = *(const float4*)(emb + (size_t)ii * EMB + c_e);        // emb(t+4)
        int t6 = t + 6 < SEQLEN ? t + 6 : SEQLEN - 1;
        idxP = mid_hist[(bbase + r_e) * SEQLEN + t6];                 // idx(t+6)
        int t2 = t + 2 < SEQLEN ? t + 2 : SEQLEN - 1;
        mskR = maskP[blk * SEQLEN + t2];                              // msk(t+2)

        // ---- phase 3: MFMA  D[j_local=g4*4+r][b=l15] ----
        floatx4 az = {0,0,0,0}, ar = {0,0,0,0}, axh = {0,0,0,0}, arh = {0,0,0,0};
        #pragma unroll
        for (int kt = 0; kt < 4; ++kt) {
            az  = __builtin_amdgcn_mfma_f32_16x16x32_f16(wA[0][kt], ea[kt], az,  0,0,0);
            ar  = __builtin_amdgcn_mfma_f32_16x16x32_f16(wA[1][kt], ea[kt], ar,  0,0,0);
            axh = __builtin_amdgcn_mfma_f32_16x16x32_f16(wA[2][kt], ea[kt], axh, 0,0,0);
            az  = __builtin_amdgcn_mfma_f32_16x16x32_f16(uA[0][kt], ha[kt], az,  0,0,0);
            ar  = __builtin_amdgcn_mfma_f32_16x16x32_f16(uA[1][kt], ha[kt], ar,  0,0,0);
            arh = __builtin_amdgcn_mfma_f32_16x16x32_f16(uA[2][kt], ha[kt], arh, 0,0,0);
        }

        // ---- phase 4: gates + h update (b = l15, j = jj + r) ----
        const int mbit = (mval >> l15) & 1;
        #pragma unroll
        for (int r = 0; r < 4; ++r) {
            float z  = fast_sigmoid(az[r] + bcz[r]);
            float rg = fast_sigmoid(ar[r] + bcr[r]);
            float hh = fast_tanh(axh[r] + bih[r] + rg * (arh[r] + brh[r]));
            float hn = hh + z * (hreg[r] - hh);
            hreg[r] = mbit ? hn : hreg[r];
        }
        half4f hw = { (f16)hreg[0], (f16)hreg[1], (f16)hreg[2], (f16)hreg[3] };
        *(half4f*)&hpk[hwoff] = hw;
        __builtin_amdgcn_sched_barrier(0);
        asm volatile("s_waitcnt lgkmcnt(0)" ::: "memory");   // h/elds writes drained
        __builtin_amdgcn_s_barrier();                        // visible to all
        __builtin_amdgcn_sched_barrier(0);
    };

    #pragma unroll 1
    for (int t = 0; t < SEQLEN; t += 2) {
        step(t,     0, eE, idxE, mskE);
        step(t + 1, 1, eO, idxO, mskO);
    }

    float4 o = { hreg[0], hreg[1], hreg[2], hreg[3] };
    *(float4*)(out_user + (size_t)(bbase + l15) * HID + jj) = o;
}

// ---------------------------------------------------------------------------
extern "C" void kernel_launch(void* const* d_in, const int* in_sizes, int n_in,
                              void* d_out, int out_size, void* d_ws, size_t ws_size,
                              hipStream_t stream) {
    const int*   mid      = (const int*)d_in[0];
    const int*   mid_hist = (const int*)d_in[1];
    const int*   mask     = (const int*)d_in[2];
    const float* emb      = (const float*)d_in[3];
    const float* W        = (const float*)d_in[4];
    const float* U        = (const float*)d_in[5];
    const float* bvec     = (const float*)d_in[6];

    float* user_out = (float*)d_out;                   // [512][128]
    float* item_out = (float*)d_out + BATCH * HID;     // [512][128]

    unsigned* maskP = (unsigned*)d_ws;                 // 32*256 u32

    prep_kernel<<<32, 256, 0, stream>>>(mask, mid, emb, maskP, item_out);
    gru_fused  <<<32, 512, 0, stream>>>(mid_hist, emb, W, U, bvec, maskP, user_out);
}

// Round 3
// 353.052 us; speedup vs baseline: 1.5346x; 1.1286x over previous
//
#include <hip/hip_runtime.h>

#define BATCH  512
#define SEQLEN 256
#define EMB    128
#define HID    128

typedef _Float16 f16;
typedef __attribute__((ext_vector_type(8))) _Float16 half8;
typedef __attribute__((ext_vector_type(4))) _Float16 half4f;
typedef __attribute__((ext_vector_type(4))) float    floatx4;

#define L2E 1.44269504088896340736f
#define T2E 2.88539008177792681472f

__device__ __forceinline__ int swzB(int byte) {          // T2 XOR swizzle, 16x256B tile
    return byte ^ (((byte >> 8) & 7) << 4);
}

// ---------------------------------------------------------------------------
// K0: prep — blocks 0..31: coalesced mask pack; blocks 32..255: item gather
// ---------------------------------------------------------------------------
__global__ void prep_kernel(const int* __restrict__ mask, const int* __restrict__ mid,
                            const float* __restrict__ emb,
                            unsigned* __restrict__ maskP, float* __restrict__ item_out) {
    const int bid = blockIdx.x, tid = threadIdx.x;
    if (bid < 32) {
        __shared__ int mls[16 * 256];
        for (int i = tid; i < 16 * 256; i += 256)        // fully coalesced
            mls[i] = mask[bid * 16 * 256 + i];
        __syncthreads();
        int t = tid;                                      // 256 threads, 256 t's
        unsigned m = 0;
        #pragma unroll
        for (int r = 0; r < 16; ++r)
            m |= (unsigned)(mls[r * 256 + t] & 1) << r;
        maskP[bid * 256 + t] = m;
    } else {
        for (int i = (bid - 32) * 256 + tid; i < BATCH * EMB; i += 224 * 256) {
            int b = i >> 7, d = i & 127;
            item_out[i] = emb[(size_t)mid[b] * EMB + d];
        }
    }
}

// ---------------------------------------------------------------------------
// K1: fused gather + x-proj + GRU scan. 32 blocks x 512 thr (8 waves).
// h double-buffered (hpk[2]), emb 4-slot ring (elds[4]) -> ONE barrier/step.
// All LDS tiles XOR-swizzled (2-way max). ea(t+1) reads overlapped with gates.
// ---------------------------------------------------------------------------
__global__ __launch_bounds__(512, 2) void gru_fused(
        const int* __restrict__ mid_hist, const float* __restrict__ emb,
        const float* __restrict__ W, const float* __restrict__ U,
        const float* __restrict__ bvec, const unsigned* __restrict__ maskP,
        float* __restrict__ out_user) {
    __shared__ __align__(16) f16 hpk[2][16 * 128];
    __shared__ __align__(16) f16 elds[4][16 * 128];

    const int tid   = threadIdx.x;
    const int lane  = tid & 63;
    const int w     = tid >> 6;        // 0..7
    const int l15   = lane & 15;
    const int g4    = lane >> 4;       // 0..3
    const int blk   = blockIdx.x;
    const int bbase = blk * 16;

    // --- A-frags: rows j = p*128 + w*16 + l15, k = kt*32 + g4*8 + e ---------
    half8 uA[3][4], wA[3][4];
    #pragma unroll
    for (int p = 0; p < 3; ++p)
        #pragma unroll
        for (int kt = 0; kt < 4; ++kt) {
            half8 u, v;
            const int j = p * 128 + w * 16 + l15;
            #pragma unroll
            for (int e = 0; e < 8; ++e) {
                int k = kt * 32 + g4 * 8 + e;
                u[e] = (f16)U[k * 384 + j];
                v[e] = (f16)W[k * 384 + j];
            }
            uA[p][kt] = u; wA[p][kt] = v;
        }

    // --- pre-scaled biases for this thread's 4 j's --------------------------
    const int jj = w * 16 + g4 * 4;
    float nbz[4], nbr[4], sxh[4], srh[4];
    {
        float4 a0 = *(const float4*)(bvec + jj);
        float4 a1 = *(const float4*)(bvec + 384 + jj);
        float4 c0 = *(const float4*)(bvec + 128 + jj);
        float4 c1 = *(const float4*)(bvec + 512 + jj);
        float4 d0 = *(const float4*)(bvec + 256 + jj);
        float4 d1 = *(const float4*)(bvec + 640 + jj);
        nbz[0] = -L2E*(a0.x+a1.x); nbz[1] = -L2E*(a0.y+a1.y);
        nbz[2] = -L2E*(a0.z+a1.z); nbz[3] = -L2E*(a0.w+a1.w);
        nbr[0] = -L2E*(c0.x+c1.x); nbr[1] = -L2E*(c0.y+c1.y);
        nbr[2] = -L2E*(c0.z+c1.z); nbr[3] = -L2E*(c0.w+c1.w);
        sxh[0] =  T2E*d0.x; sxh[1] = T2E*d0.y; sxh[2] = T2E*d0.z; sxh[3] = T2E*d0.w;
        srh[0] =  T2E*d1.x; srh[1] = T2E*d1.y; srh[2] = T2E*d1.z; srh[3] = T2E*d1.w;
    }

    // --- swizzled offsets (f16 elems) ---------------------------------------
    int aswz[4];
    #pragma unroll
    for (int kt = 0; kt < 4; ++kt)
        aswz[kt] = swzB(l15 * 256 + kt * 64 + g4 * 16) >> 1;
    const int hswz = swzB(l15 * 256 + jj * 2) >> 1;
    const int r_e  = tid >> 5;          // 0..15 staging row
    const int c32  = tid & 31;          // float4 chunk
    const int sswz = swzB(r_e * 256 + c32 * 8) >> 1;
    const int histbase = (bbase + r_e) * SEQLEN;
    const int mpbase   = blk * SEQLEN;

    for (int i = tid; i < 16 * 128; i += 512) hpk[0][i] = (f16)0.f;  // h0 = 0

    // --- prologue: stage emb(0),emb(1) into slots 0,1; rings ----------------
    {
        int i0 = mid_hist[histbase + 0];
        int i1 = mid_hist[histbase + 1];
        float4 v0 = *(const float4*)(emb + (size_t)i0 * EMB + c32 * 4);
        float4 v1 = *(const float4*)(emb + (size_t)i1 * EMB + c32 * 4);
        *(half4f*)&elds[0][sswz] = half4f{(f16)v0.x,(f16)v0.y,(f16)v0.z,(f16)v0.w};
        *(half4f*)&elds[1][sswz] = half4f{(f16)v1.x,(f16)v1.y,(f16)v1.z,(f16)v1.w};
    }
    int i2 = mid_hist[histbase + 2];
    int i3 = mid_hist[histbase + 3];
    float4   Ee = *(const float4*)(emb + (size_t)i2 * EMB + c32 * 4);  // emb(2)
    float4   Eo = *(const float4*)(emb + (size_t)i3 * EMB + c32 * 4);  // emb(3)
    int      Ie = mid_hist[histbase + 4];                              // idx(4)
    int      Io = mid_hist[histbase + 5];                              // idx(5)
    unsigned Me = maskP[mpbase + 0];                                   // msk(0)
    unsigned Mo = maskP[mpbase + 1];                                   // msk(1)

    float hreg[4] = {0.f, 0.f, 0.f, 0.f};
    __syncthreads();

    // ea(0) preloaded before loop
    half8 ea[4];
    #pragma unroll
    for (int kt = 0; kt < 4; ++kt) ea[kt] = *(const half8*)&elds[0][aswz[kt]];

    auto step = [&](int t, float4& E, int& I, unsigned& M) {
        const f16* hrd = hpk[t & 1];
        f16*       hwr = hpk[(t + 1) & 1];
        // ---- ha frag reads (the only LDS on the critical path) ----
        half8 ha[4];
        #pragma unroll
        for (int kt = 0; kt < 4; ++kt) ha[kt] = *(const half8*)&hrd[aswz[kt]];

        // ---- MFMA: 12 ea-MFMAs first (no wait), then 12 ha-MFMAs ----
        floatx4 az = {0,0,0,0}, ar = {0,0,0,0}, axh = {0,0,0,0}, arh = {0,0,0,0};
        #pragma unroll
        for (int kt = 0; kt < 4; ++kt) {
            az  = __builtin_amdgcn_mfma_f32_16x16x32_f16(wA[0][kt], ea[kt], az,  0,0,0);
            ar  = __builtin_amdgcn_mfma_f32_16x16x32_f16(wA[1][kt], ea[kt], ar,  0,0,0);
            axh = __builtin_amdgcn_mfma_f32_16x16x32_f16(wA[2][kt], ea[kt], axh, 0,0,0);
        }
        #pragma unroll
        for (int kt = 0; kt < 4; ++kt) {
            az  = __builtin_amdgcn_mfma_f32_16x16x32_f16(uA[0][kt], ha[kt], az,  0,0,0);
            ar  = __builtin_amdgcn_mfma_f32_16x16x32_f16(uA[1][kt], ha[kt], ar,  0,0,0);
            arh = __builtin_amdgcn_mfma_f32_16x16x32_f16(uA[2][kt], ha[kt], arh, 0,0,0);
        }

        // ---- overlapped: recycle elds ring, reissue prefetches, ea(t+1) ----
        *(half4f*)&elds[(t + 2) & 3][sswz] =
            half4f{(f16)E.x, (f16)E.y, (f16)E.z, (f16)E.w};            // emb(t+2)
        int ii = I;
        E = *(const float4*)(emb + (size_t)ii * EMB + c32 * 4);        // emb(t+4)
        int t6 = t + 6 < SEQLEN ? t + 6 : SEQLEN - 1;
        I = mid_hist[histbase + t6];                                   // idx(t+6)
        unsigned mval = M;
        M = maskP[mpbase + t + 2];                                     // msk(t+2)
        {
            const f16* erd = elds[(t + 1) & 3];
            #pragma unroll
            for (int kt = 0; kt < 4; ++kt) ea[kt] = *(const half8*)&erd[aswz[kt]];
        }

        // ---- gates + h update (b = l15, j = jj + r) ----
        const int mbit = (mval >> l15) & 1;
        #pragma unroll
        for (int r = 0; r < 4; ++r) {
            float z  = __builtin_amdgcn_rcpf(1.f + __builtin_amdgcn_exp2f(__builtin_fmaf(az[r], -L2E, nbz[r])));
            float rg = __builtin_amdgcn_rcpf(1.f + __builtin_amdgcn_exp2f(__builtin_fmaf(ar[r], -L2E, nbr[r])));
            float u  = __builtin_fmaf(rg, __builtin_fmaf(arh[r], T2E, srh[r]),
                                          __builtin_fmaf(axh[r], T2E, sxh[r]));
            float hh = __builtin_fmaf(-2.f, __builtin_amdgcn_rcpf(__builtin_amdgcn_exp2f(u) + 1.f), 1.f);
            float hn = __builtin_fmaf(z, hreg[r] - hh, hh);
            hreg[r]  = mbit ? hn : hreg[r];
        }
        *(half4f*)&hwr[hswz] = half4f{(f16)hreg[0], (f16)hreg[1], (f16)hreg[2], (f16)hreg[3]};

        __builtin_amdgcn_sched_barrier(0);
        asm volatile("s_waitcnt lgkmcnt(0)" ::: "memory");  // LDS writes + ea reads done
        __builtin_amdgcn_s_barrier();                       // ONE barrier per step
        __builtin_amdgcn_sched_barrier(0);
    };

    #pragma unroll 1
    for (int t = 0; t < SEQLEN; t += 2) {
        step(t,     Ee, Ie, Me);
        step(t + 1, Eo, Io, Mo);
    }

    float4 o = { hreg[0], hreg[1], hreg[2], hreg[3] };
    *(float4*)(out_user + (size_t)(bbase + l15) * HID + jj) = o;
}

// ---------------------------------------------------------------------------
extern "C" void kernel_launch(void* const* d_in, const int* in_sizes, int n_in,
                              void* d_out, int out_size, void* d_ws, size_t ws_size,
                              hipStream_t stream) {
    const int*   mid      = (const int*)d_in[0];
    const int*   mid_hist = (const int*)d_in[1];
    const int*   mask     = (const int*)d_in[2];
    const float* emb      = (const float*)d_in[3];
    const float* W        = (const float*)d_in[4];
    const float* U        = (const float*)d_in[5];
    const float* bvec     = (const float*)d_in[6];

    float* user_out = (float*)d_out;                   // [512][128]
    float* item_out = (float*)d_out + BATCH * HID;     // [512][128]

    unsigned* maskP = (unsigned*)d_ws;                 // 32*256 u32

    prep_kernel<<<256, 256, 0, stream>>>(mask, mid, emb, maskP, item_out);
    gru_fused  <<<32, 512, 0, stream>>>(mid_hist, emb, W, U, bvec, maskP, user_out);
}